// Round 5
// baseline (29.125 us; speedup 1.0000x reference)
//
#include <hip/hip_runtime.h>
#include <math.h>

// out[b, i, h, w] = (1/W) * ( cos(2pi*i*w/W)*c[b,h,i] + sin(2pi*i*w/W)*s[b,h,i] )
// c[b,h,i] = sum_w' x[b,h,w'] cos(2pi*i*w'/W), s likewise with sin.
//
// Block = (b, i, h-quarter): computes c,s for its 32 rows at its single
// frequency i (exact partition of DFT work), then writes a CONTIGUOUS
// 16 KB slab out[b, i, 32q:32q+32, :]  -> fill-kernel-like page locality.
// Trig: native v_sin/v_cos on &127-reduced angles + short rotation chains.

#define WDIM 128
#define BLK 256
#define PI_OVER_64 0.04908738521234052f   // 2*pi/128

typedef float vfloat4 __attribute__((ext_vector_type(4)));

__global__ __launch_bounds__(BLK) void kspace_map_kernel(
    const float* __restrict__ in, float* __restrict__ out) {
    const int blk = blockIdx.x;        // 0..8191, i fastest
    const int i   = blk & 127;         // frequency / output plane index
    const int bq  = blk >> 7;          // 0..63
    const int q   = bq & 3;            // h-quarter
    const int b   = bq >> 2;           // batch

    __shared__ float cS[32];
    __shared__ float sS[32];

    const int t = threadIdx.x;

    // ---- phase 1: c,s for h in [32q,32q+32) at frequency i ----
    // thread = (hl = t>>3, seg = t&7); 16-term chain over k in [16seg,16seg+16)
    const int hl  = t >> 3;
    const int seg = t & 7;
    const int k0  = seg << 4;
    const int h   = (q << 5) + hl;

    const float stepA = (float)i * PI_OVER_64;
    const float stC = __cosf(stepA);
    const float stS = __sinf(stepA);

    {
        const float* xr = in + ((size_t)b << 14) + ((size_t)h << 7) + k0;
        vfloat4 x0 = *(const vfloat4*)(xr + 0);
        vfloat4 x1 = *(const vfloat4*)(xr + 4);
        vfloat4 x2 = *(const vfloat4*)(xr + 8);
        vfloat4 x3 = *(const vfloat4*)(xr + 12);

        const int idx0 = (i * k0) & 127;
        float C = __cosf((float)idx0 * PI_OVER_64);
        float S = __sinf((float)idx0 * PI_OVER_64);

        float cc = 0.0f, ss = 0.0f;
        float xs[16];
        *reinterpret_cast<vfloat4*>(&xs[0])  = x0;
        *reinterpret_cast<vfloat4*>(&xs[4])  = x1;
        *reinterpret_cast<vfloat4*>(&xs[8])  = x2;
        *reinterpret_cast<vfloat4*>(&xs[12]) = x3;
        #pragma unroll
        for (int k = 0; k < 16; ++k) {
            const float xv = xs[k];
            cc = fmaf(xv, C, cc);
            ss = fmaf(xv, S, ss);
            const float nC = fmaf(C, stC, -(S * stS));
            const float nS = fmaf(S, stC,  (C * stS));
            C = nC; S = nS;
        }
        // reduce the 8 seg-partials within each 8-lane group
        #pragma unroll
        for (int m = 1; m <= 4; m <<= 1) {
            cc += __shfl_xor(cc, m);
            ss += __shfl_xor(ss, m);
        }
        if (seg == 0) { cS[hl] = cc; sS[hl] = ss; }
    }
    __syncthreads();

    // ---- phase 2: contiguous 16 KB slab out[b, i, 32q+hp, w] ----
    const float invW = 1.0f / (float)WDIM;
    const int col = t & 31;
    const int w0  = col << 2;          // 0,4,...,124 (fixed per thread)
    const int r   = t >> 5;            // 0..7

    // trig at (i, w0..w0+3): computed once, reused for all rows
    const int j0 = (i * w0) & 127;
    const float Cv0 = __cosf((float)j0 * PI_OVER_64);
    const float Sv0 = __sinf((float)j0 * PI_OVER_64);
    const float Cv1 = fmaf(Cv0, stC, -(Sv0 * stS));
    const float Sv1 = fmaf(Sv0, stC,  (Cv0 * stS));
    const float Cv2 = fmaf(Cv1, stC, -(Sv1 * stS));
    const float Sv2 = fmaf(Sv1, stC,  (Cv1 * stS));
    const float Cv3 = fmaf(Cv2, stC, -(Sv2 * stS));
    const float Sv3 = fmaf(Sv2, stC,  (Cv2 * stS));

    // slab base: b*2^21 + i*2^14 + q*4096
    float* op = out + ((size_t)b << 21) + ((size_t)i << 14) + ((size_t)q << 12);

    #pragma unroll
    for (int ii = 0; ii < 4; ++ii) {
        const int hp = (ii << 3) + r;          // 0..31
        const float ci = cS[hp] * invW;        // per-wave broadcast (2 addrs)
        const float si = sS[hp] * invW;
        vfloat4 v;
        v.x = fmaf(ci, Cv0, si * Sv0);
        v.y = fmaf(ci, Cv1, si * Sv1);
        v.z = fmaf(ci, Cv2, si * Sv2);
        v.w = fmaf(ci, Cv3, si * Sv3);
        __builtin_nontemporal_store(
            v, reinterpret_cast<vfloat4*>(op + ((size_t)hp << 7) + w0));
    }
}

extern "C" void kernel_launch(void* const* d_in, const int* in_sizes, int n_in,
                              void* d_out, int out_size, void* d_ws, size_t ws_size,
                              hipStream_t stream) {
    const float* in = (const float*)d_in[0];   // (16,1,128,128) fp32
    float* out = (float*)d_out;                // (16,128,128,128) fp32
    dim3 grid(16 * 4 * 128);                   // (b,q) major, i fastest
    dim3 block(BLK);
    hipLaunchKernelGGL(kspace_map_kernel, grid, block, 0, stream, in, out);
}

// Round 6
// 28.118 us; speedup vs baseline: 1.0358x; 1.0358x over previous
//
#include <hip/hip_runtime.h>
#include <math.h>

// out[b, i, h, w] = (1/W) * ( cos(2pi*i*w/W)*c[b,h,i] + sin(2pi*i*w/W)*s[b,h,i] )
// c[b,h,i] = sum_w' x[b,h,w'] cos(2pi*i*w'/W), s likewise with sin.
//
// Block = (b, i, h-quarter): computes c,s for its 32 rows at its single
// frequency i, then writes a CONTIGUOUS 16 KB slab out[b, i, 32q:32q+32, :].
// R5 change vs R4: NORMAL stores (through L2) instead of nontemporal —
// isolating the NT flag as the suspected regression cause.

#define WDIM 128
#define BLK 256
#define PI_OVER_64 0.04908738521234052f   // 2*pi/128

typedef float vfloat4 __attribute__((ext_vector_type(4)));

__global__ __launch_bounds__(BLK) void kspace_map_kernel(
    const float* __restrict__ in, float* __restrict__ out) {
    const int blk = blockIdx.x;        // 0..8191, i fastest
    const int i   = blk & 127;         // frequency / output plane index
    const int bq  = blk >> 7;          // 0..63
    const int q   = bq & 3;            // h-quarter
    const int b   = bq >> 2;           // batch

    __shared__ float cS[32];
    __shared__ float sS[32];

    const int t = threadIdx.x;

    // ---- phase 1: c,s for h in [32q,32q+32) at frequency i ----
    // thread = (hl = t>>3, seg = t&7); 16-term chain over k in [16seg,16seg+16)
    const int hl  = t >> 3;
    const int seg = t & 7;
    const int k0  = seg << 4;
    const int h   = (q << 5) + hl;

    // issue the input loads FIRST so L2 latency hides under trig setup
    const float* xr = in + ((size_t)b << 14) + ((size_t)h << 7) + k0;
    vfloat4 x0 = *(const vfloat4*)(xr + 0);
    vfloat4 x1 = *(const vfloat4*)(xr + 4);
    vfloat4 x2 = *(const vfloat4*)(xr + 8);
    vfloat4 x3 = *(const vfloat4*)(xr + 12);

    const float stepA = (float)i * PI_OVER_64;
    const float stC = __cosf(stepA);
    const float stS = __sinf(stepA);

    {
        const int idx0 = (i * k0) & 127;
        float C = __cosf((float)idx0 * PI_OVER_64);
        float S = __sinf((float)idx0 * PI_OVER_64);

        float cc = 0.0f, ss = 0.0f;
        float xs[16];
        *reinterpret_cast<vfloat4*>(&xs[0])  = x0;
        *reinterpret_cast<vfloat4*>(&xs[4])  = x1;
        *reinterpret_cast<vfloat4*>(&xs[8])  = x2;
        *reinterpret_cast<vfloat4*>(&xs[12]) = x3;
        #pragma unroll
        for (int k = 0; k < 16; ++k) {
            const float xv = xs[k];
            cc = fmaf(xv, C, cc);
            ss = fmaf(xv, S, ss);
            const float nC = fmaf(C, stC, -(S * stS));
            const float nS = fmaf(S, stC,  (C * stS));
            C = nC; S = nS;
        }
        // reduce the 8 seg-partials within each 8-lane group
        #pragma unroll
        for (int m = 1; m <= 4; m <<= 1) {
            cc += __shfl_xor(cc, m);
            ss += __shfl_xor(ss, m);
        }
        if (seg == 0) { cS[hl] = cc; sS[hl] = ss; }
    }
    __syncthreads();

    // ---- phase 2: contiguous 16 KB slab out[b, i, 32q+hp, w] ----
    const float invW = 1.0f / (float)WDIM;
    const int col = t & 31;
    const int w0  = col << 2;          // 0,4,...,124 (fixed per thread)
    const int r   = t >> 5;            // 0..7

    // trig at (i, w0..w0+3): computed once, reused for all rows
    const int j0 = (i * w0) & 127;
    const float Cv0 = __cosf((float)j0 * PI_OVER_64);
    const float Sv0 = __sinf((float)j0 * PI_OVER_64);
    const float Cv1 = fmaf(Cv0, stC, -(Sv0 * stS));
    const float Sv1 = fmaf(Sv0, stC,  (Cv0 * stS));
    const float Cv2 = fmaf(Cv1, stC, -(Sv1 * stS));
    const float Sv2 = fmaf(Sv1, stC,  (Cv1 * stS));
    const float Cv3 = fmaf(Cv2, stC, -(Sv2 * stS));
    const float Sv3 = fmaf(Sv2, stC,  (Cv2 * stS));

    // slab base: b*2^21 + i*2^14 + q*4096
    float* op = out + ((size_t)b << 21) + ((size_t)i << 14) + ((size_t)q << 12);

    #pragma unroll
    for (int ii = 0; ii < 4; ++ii) {
        const int hp = (ii << 3) + r;          // 0..31
        const float ci = cS[hp] * invW;        // per-wave broadcast (2 addrs)
        const float si = sS[hp] * invW;
        vfloat4 v;
        v.x = fmaf(ci, Cv0, si * Sv0);
        v.y = fmaf(ci, Cv1, si * Sv1);
        v.z = fmaf(ci, Cv2, si * Sv2);
        v.w = fmaf(ci, Cv3, si * Sv3);
        *reinterpret_cast<vfloat4*>(op + ((size_t)hp << 7) + w0) = v;
    }
}

extern "C" void kernel_launch(void* const* d_in, const int* in_sizes, int n_in,
                              void* d_out, int out_size, void* d_ws, size_t ws_size,
                              hipStream_t stream) {
    const float* in = (const float*)d_in[0];   // (16,1,128,128) fp32
    float* out = (float*)d_out;                // (16,128,128,128) fp32
    dim3 grid(16 * 4 * 128);                   // (b,q) major, i fastest
    dim3 block(BLK);
    hipLaunchKernelGGL(kspace_map_kernel, grid, block, 0, stream, in, out);
}